// Round 5
// baseline (358.303 us; speedup 1.0000x reference)
//
#include <hip/hip_runtime.h>

#define B_ 64
#define N_ 256
#define V_ 2048
#define E_ 1024
#define MROWS 16384  // B_*N_

typedef __bf16 bf16_t;
typedef bf16_t bf16x8 __attribute__((ext_vector_type(8)));
typedef float f32x4 __attribute__((ext_vector_type(4)));

// ws layout (float units):
#define OFF_S   0         // s      [16384]
#define OFF_LR  16384     // LR     [16384*128]
#define OFF_FT  2113536   // featsT [2048*64]
#define OFF_WB  2244608   // Wb bf16[128*2048] (= 131072 floats)

// ---------------- kernel 1: weight-norm scale folded into bf16 weights ----
// also zeroes featsT (removes a separate memset dispatch)
__global__ void kprep(const float* __restrict__ U1v, const float* __restrict__ U1g,
                      const float* __restrict__ U2v, const float* __restrict__ U2g,
                      bf16_t* __restrict__ Wb, float* __restrict__ featsT) {
    {
        float4 z = {0.f, 0.f, 0.f, 0.f};
        *(float4*)&featsT[(size_t)(blockIdx.x * 256 + threadIdx.x) * 4] = z;
    }
    __shared__ float red[256];
    __shared__ float sc;
    const int r = blockIdx.x;  // 0..127
    const float* v = (r < 64) ? (U1v + (size_t)r * V_) : (U2v + (size_t)(r - 64) * V_);
    float ss = 0.f;
    for (int i = threadIdx.x; i < V_; i += 256) { float x = v[i]; ss += x * x; }
    red[threadIdx.x] = ss;
    __syncthreads();
    for (int o = 128; o > 0; o >>= 1) {
        if (threadIdx.x < (unsigned)o) red[threadIdx.x] += red[threadIdx.x + o];
        __syncthreads();
    }
    if (threadIdx.x == 0) {
        float g = (r < 64) ? U1g[r] : U2g[r - 64];
        sc = g * rsqrtf(red[0]);
    }
    __syncthreads();
    const float s = sc;
    const int k = threadIdx.x * 8;
    float4 f0 = *(const float4*)(v + k);
    float4 f1 = *(const float4*)(v + k + 4);
    bf16x8 o;
    o[0] = (bf16_t)(f0.x * s); o[1] = (bf16_t)(f0.y * s);
    o[2] = (bf16_t)(f0.z * s); o[3] = (bf16_t)(f0.w * s);
    o[4] = (bf16_t)(f1.x * s); o[5] = (bf16_t)(f1.y * s);
    o[6] = (bf16_t)(f1.z * s); o[7] = (bf16_t)(f1.w * s);
    *(bf16x8*)(Wb + (size_t)r * V_ + k) = o;
}

// ---------------- kernel 2: barrier-free direct-register MFMA GEMM --------
// LR[16384x128] = relu(Vmat * Wb^T + bias). Grid 512 x 256 thr (4 waves).
// Block m-tile = 32 rows; wave w -> n in [32w, 32w+32). NO LDS, NO barriers
// in the K-loop (except a drift-bounding sync every 8 iters): A fragments
// loaded per-lane direct from global fp32 (16 rows x 128B windows, fully
// coalesced) and converted to bf16 in-reg; B fragments direct from global
// bf16 (512KB total, L2-resident, shared by all blocks via L1/L2).
// Fragment layout (16x16x32): row = lane&15, k = (lane>>4)*8 + j.
__global__ __launch_bounds__(256) void gemm_lr(
    const float* __restrict__ V, const bf16_t* __restrict__ Wb,
    const float* __restrict__ U1b, const float* __restrict__ U2b,
    float* __restrict__ LR) {
    const int t = threadIdx.x;
    const int m0 = blockIdx.x * 32;
    const int wv = t >> 6, lane = t & 63;
    const int lm = lane & 15, lq = lane >> 4;
    const int n0w = wv * 32;

    const float*  a0p = V  + (size_t)(m0 + lm) * V_ + lq * 8;
    const float*  a1p = a0p + (size_t)16 * V_;
    const bf16_t* b0p = Wb + (size_t)(n0w + lm) * V_ + lq * 8;
    const bf16_t* b1p = b0p + (size_t)16 * V_;

    f32x4 acc[2][2];
#pragma unroll
    for (int i = 0; i < 2; ++i)
#pragma unroll
        for (int j = 0; j < 2; ++j) acc[i][j] = (f32x4){0.f, 0.f, 0.f, 0.f};

    for (int k0 = 0; k0 < V_; k0 += 64) {
#pragma unroll
        for (int h = 0; h < 2; ++h) {
            const int k = k0 + h * 32;
            float4 x00 = *(const float4*)(a0p + k);
            float4 x01 = *(const float4*)(a0p + k + 4);
            float4 x10 = *(const float4*)(a1p + k);
            float4 x11 = *(const float4*)(a1p + k + 4);
            bf16x8 bf0 = *(const bf16x8*)(b0p + k);
            bf16x8 bf1 = *(const bf16x8*)(b1p + k);
            bf16x8 af0, af1;
            af0[0] = (bf16_t)x00.x; af0[1] = (bf16_t)x00.y; af0[2] = (bf16_t)x00.z; af0[3] = (bf16_t)x00.w;
            af0[4] = (bf16_t)x01.x; af0[5] = (bf16_t)x01.y; af0[6] = (bf16_t)x01.z; af0[7] = (bf16_t)x01.w;
            af1[0] = (bf16_t)x10.x; af1[1] = (bf16_t)x10.y; af1[2] = (bf16_t)x10.z; af1[3] = (bf16_t)x10.w;
            af1[4] = (bf16_t)x11.x; af1[5] = (bf16_t)x11.y; af1[6] = (bf16_t)x11.z; af1[7] = (bf16_t)x11.w;
            acc[0][0] = __builtin_amdgcn_mfma_f32_16x16x32_bf16(af0, bf0, acc[0][0], 0, 0, 0);
            acc[0][1] = __builtin_amdgcn_mfma_f32_16x16x32_bf16(af0, bf1, acc[0][1], 0, 0, 0);
            acc[1][0] = __builtin_amdgcn_mfma_f32_16x16x32_bf16(af1, bf0, acc[1][0], 0, 0, 0);
            acc[1][1] = __builtin_amdgcn_mfma_f32_16x16x32_bf16(af1, bf1, acc[1][1], 0, 0, 0);
        }
        // bound wave drift within the block so the 4 waves keep sharing
        // the same A cachelines through L1 (every 8 K-iters)
        if (((k0 >> 6) & 7) == 7) __syncthreads();
    }
    // epilogue: bias + relu. C/D: n = lane&15 (+16j), m = lq*4 + reg (+16i)
#pragma unroll
    for (int j = 0; j < 2; ++j) {
        const int n = n0w + j * 16 + lm;
        const float bi = (n < 64) ? U1b[n] : U2b[n - 64];
#pragma unroll
        for (int i = 0; i < 2; ++i)
#pragma unroll
            for (int r = 0; r < 4; ++r) {
                const int m = m0 + i * 16 + lq * 4 + r;
                LR[(size_t)m * 128 + n] = fmaxf(acc[i][j][r] + bi, 0.f);
            }
    }
}

// ---------------- kernel 3: fused d + Lbar + s (per batch) ----------------
__global__ __launch_bounds__(256) void kds(const float* __restrict__ LR, float* __restrict__ s) {
    __shared__ float dl[256];
    __shared__ float red[4][64];
    __shared__ float lbar[64];
    const int b = blockIdx.x, t = threadIdx.x;
    const float* Lb = LR + (size_t)b * N_ * 128;
    const float* row = Lb + (size_t)t * 128;
    float dd = 0.f;
#pragma unroll
    for (int k = 0; k < 64; k += 4) {
        float4 l = *(const float4*)(row + k);
        float4 r = *(const float4*)(row + 64 + k);
        dd += l.x * r.x + l.y * r.y + l.z * r.z + l.w * r.w;
    }
    const float dv = rsqrtf(dd + 1e-6f);
    dl[t] = dv;
    __syncthreads();
    const int k = t & 63, g = t >> 6;
    float acc = 0.f;
    for (int n = g; n < N_; n += 4)
        acc += dl[n] * Lb[(size_t)n * 128 + 64 + k];
    red[g][k] = acc;
    __syncthreads();
    if (t < 64) lbar[t] = red[0][t] + red[1][t] + red[2][t] + red[3][t];
    __syncthreads();
    float a2 = 0.f;
#pragma unroll 8
    for (int kk = 0; kk < 64; ++kk) a2 += lbar[kk] * row[kk];
    s[b * N_ + t] = ((float)(N_ + 1) - dv * a2) * (1.0f / (float)N_);
}

// ---------------- kernel 4: featsT[v][b] += partial over m-chunk ----------
__global__ __launch_bounds__(256) void kfeats(const float* __restrict__ Vmat,
                                              const float* __restrict__ s,
                                              float* __restrict__ featsT) {
    const int b = blockIdx.x >> 3, vc = (blockIdx.x >> 2) & 1, mc = blockIdx.x & 3;
    __shared__ float sl[64];
    const int t = threadIdx.x;
    if (t < 64) sl[t] = s[b * N_ + mc * 64 + t];
    __syncthreads();
    const int v = vc * 1024 + t * 4;
    const float* base = Vmat + (size_t)b * N_ * V_ + (size_t)mc * 64 * V_ + v;
    float4 a = {0.f, 0.f, 0.f, 0.f};
    for (int m = 0; m < 64; m += 8) {
        float4 x[8];
#pragma unroll
        for (int u = 0; u < 8; ++u) x[u] = *(const float4*)(base + (size_t)(m + u) * V_);
#pragma unroll
        for (int u = 0; u < 8; ++u) {
            float sv = sl[m + u];
            a.x += sv * x[u].x; a.y += sv * x[u].y;
            a.z += sv * x[u].z; a.w += sv * x[u].w;
        }
    }
    atomicAdd(&featsT[(size_t)(v + 0) * 64 + b], a.x);
    atomicAdd(&featsT[(size_t)(v + 1) * 64 + b], a.y);
    atomicAdd(&featsT[(size_t)(v + 2) * 64 + b], a.z);
    atomicAdd(&featsT[(size_t)(v + 3) * 64 + b], a.w);
}

// ---------------- kernel 5: fused linear + BatchNorm ----------------------
// (b_lin dropped: constant per-column shift cancels in BatchNorm)
__global__ __launch_bounds__(256) void klinbn(const float* __restrict__ featsT,
                                              const float* __restrict__ Wl,
                                              const float* __restrict__ gamma,
                                              const float* __restrict__ beta,
                                              float* __restrict__ out) {
    __shared__ float red[4][4][64];
    const int e0 = blockIdx.x * 4;
    const int t = threadIdx.x, b = t & 63, g = t >> 6;
    const float* w0 = Wl + (size_t)(e0 + 0) * V_ + g * 512;
    const float* w1 = Wl + (size_t)(e0 + 1) * V_ + g * 512;
    const float* w2 = Wl + (size_t)(e0 + 2) * V_ + g * 512;
    const float* w3 = Wl + (size_t)(e0 + 3) * V_ + g * 512;
    const float* f = featsT + (size_t)g * 512 * 64 + b;
    float a0 = 0.f, a1 = 0.f, a2 = 0.f, a3 = 0.f;
#pragma unroll 4
    for (int k = 0; k < 512; ++k) {
        float fv = f[(size_t)k * 64];
        a0 += fv * w0[k]; a1 += fv * w1[k]; a2 += fv * w2[k]; a3 += fv * w3[k];
    }
    red[g][0][b] = a0; red[g][1][b] = a1; red[g][2][b] = a2; red[g][3][b] = a3;
    __syncthreads();
    const int e = t >> 6;  // wave e owns e-row e0+e across lanes b
    float v = red[0][e][b] + red[1][e][b] + red[2][e][b] + red[3][e][b];
    float sum = v;
#pragma unroll
    for (int o = 1; o < 64; o <<= 1) sum += __shfl_xor(sum, o, 64);
    float mu = sum * (1.f / 64.f);
    float dvv = v - mu;
    float q = dvv * dvv;
#pragma unroll
    for (int o = 1; o < 64; o <<= 1) q += __shfl_xor(q, o, 64);
    float inv = rsqrtf(q * (1.f / 64.f) + 1e-5f);
    float res = gamma[e0 + e] * dvv * inv + beta[e0 + e];
    __syncthreads();
    red[0][e][b] = res;
    __syncthreads();
    const int b2 = t >> 2, j = t & 3;
    out[(size_t)b2 * E_ + e0 + j] = red[0][j][b2];
}

extern "C" void kernel_launch(void* const* d_in, const int* in_sizes, int n_in,
                              void* d_out, int out_size, void* d_ws, size_t ws_size,
                              hipStream_t stream) {
    const float* Vmat = (const float*)d_in[0];
    const float* U1v  = (const float*)d_in[1];
    const float* U1g  = (const float*)d_in[2];
    const float* U1b  = (const float*)d_in[3];
    const float* U2v  = (const float*)d_in[4];
    const float* U2g  = (const float*)d_in[5];
    const float* U2b  = (const float*)d_in[6];
    const float* Wl   = (const float*)d_in[7];
    // d_in[8] = b_lin: unused (cancels in BatchNorm)
    const float* gam  = (const float*)d_in[9];
    const float* bet  = (const float*)d_in[10];

    float*  ws     = (float*)d_ws;
    float*  s      = ws + OFF_S;
    float*  LR     = ws + OFF_LR;
    float*  featsT = ws + OFF_FT;
    bf16_t* Wb     = (bf16_t*)(ws + OFF_WB);

    kprep  <<<128, 256, 0, stream>>>(U1v, U1g, U2v, U2g, Wb, featsT);
    gemm_lr<<<MROWS / 32, 256, 0, stream>>>(Vmat, Wb, U1b, U2b, LR);
    kds    <<<B_, 256, 0, stream>>>(LR, s);
    kfeats <<<B_ * 8, 256, 0, stream>>>(Vmat, s, featsT);
    klinbn <<<E_ / 4, 256, 0, stream>>>(featsT, Wl, gam, bet, (float*)d_out);
}

// Round 6
// 335.092 us; speedup vs baseline: 1.0693x; 1.0693x over previous
//
#include <hip/hip_runtime.h>

#define B_ 64
#define N_ 256
#define V_ 2048
#define E_ 1024
#define MROWS 16384  // B_*N_

typedef __bf16 bf16_t;
typedef bf16_t bf16x8 __attribute__((ext_vector_type(8)));
typedef float f32x4 __attribute__((ext_vector_type(4)));

// ws layout (float units):
#define OFF_S   0          // s      [16384]
#define OFF_LR  16384      // LR partials: 2 x [16384*128]
#define OFF_FT  4210688    // featsT [2048*64]
#define OFF_WB  4341760    // Wb bf16[128*2048] (= 131072 floats)
#define LRHALF  2097152    // floats per K-half partial

__device__ __forceinline__ void gload_lds16(const bf16_t* g, bf16_t* l) {
    __builtin_amdgcn_global_load_lds((const __attribute__((address_space(1))) void*)g,
                                     (__attribute__((address_space(3))) void*)l, 16, 0, 0);
}

// ---------------- kernel 1: weight-norm scale folded into bf16 weights ----
// also zeroes featsT (removes a separate memset dispatch)
__global__ void kprep(const float* __restrict__ U1v, const float* __restrict__ U1g,
                      const float* __restrict__ U2v, const float* __restrict__ U2g,
                      bf16_t* __restrict__ Wb, float* __restrict__ featsT) {
    {
        float4 z = {0.f, 0.f, 0.f, 0.f};
        *(float4*)&featsT[(size_t)(blockIdx.x * 256 + threadIdx.x) * 4] = z;
    }
    __shared__ float red[256];
    __shared__ float sc;
    const int r = blockIdx.x;  // 0..127
    const float* v = (r < 64) ? (U1v + (size_t)r * V_) : (U2v + (size_t)(r - 64) * V_);
    float ss = 0.f;
    for (int i = threadIdx.x; i < V_; i += 256) { float x = v[i]; ss += x * x; }
    red[threadIdx.x] = ss;
    __syncthreads();
    for (int o = 128; o > 0; o >>= 1) {
        if (threadIdx.x < (unsigned)o) red[threadIdx.x] += red[threadIdx.x + o];
        __syncthreads();
    }
    if (threadIdx.x == 0) {
        float g = (r < 64) ? U1g[r] : U2g[r - 64];
        sc = g * rsqrtf(red[0]);
    }
    __syncthreads();
    const float s = sc;
    const int k = threadIdx.x * 8;
    float4 f0 = *(const float4*)(v + k);
    float4 f1 = *(const float4*)(v + k + 4);
    bf16x8 o;
    o[0] = (bf16_t)(f0.x * s); o[1] = (bf16_t)(f0.y * s);
    o[2] = (bf16_t)(f0.z * s); o[3] = (bf16_t)(f0.w * s);
    o[4] = (bf16_t)(f1.x * s); o[5] = (bf16_t)(f1.y * s);
    o[6] = (bf16_t)(f1.z * s); o[7] = (bf16_t)(f1.w * s);
    *(bf16x8*)(Wb + (size_t)r * V_ + k) = o;
}

// ---------------- kernel 2: MFMA bf16 projections, split-K x2 -------------
// LRp[ky][16384x128] = Vmat[:, kyhalf] * Wb[:, kyhalf]^T  (raw, no bias/relu)
// Tile 32m x 128n, BK=64, grid (512, 2) -> 4 blocks/CU for latency hiding.
// Proven R3 structure: B via global_load_lds dwordx4, A reg-prefetch+convert,
// XOR-swizzled LDS (conflict-free), two barriers per K-iter.
#define BK 64
#define KHALF 1024
__global__ __launch_bounds__(256) void gemm_lr(
    const float* __restrict__ V, const bf16_t* __restrict__ Wb,
    float* __restrict__ LRp) {
    __shared__ bf16_t As[32 * BK];
    __shared__ bf16_t Bs[128 * BK];
    const int t = threadIdx.x;
    const int m0 = blockIdx.x * 32;
    const int kbase = blockIdx.y * KHALF;
    float* LRh = LRp + (size_t)blockIdx.y * LRHALF;
    const int wv = t >> 6, lane = t & 63;
    const int lm = lane & 15, lq = lane >> 4;
    const int n0w = wv * 32;

    // A staging: thread -> (row 0..31, 8-elem chunk au 0..7), XOR swizzle
    const int arow = t >> 3, au = t & 7;
    const float* aptr = V + (size_t)(m0 + arow) * V_ + kbase + au * 8;
    bf16_t* adst = &As[arow * BK + ((au ^ (arow & 7)) * 8)];

    // B DMA: lane -> (row = q*32 + wv*8 + rloc, swizzled chunk uu)
    const int rloc = lane >> 3;
    const int uu = (lane & 7) ^ rloc;
    const bf16_t* bgbase = Wb + (size_t)(wv * 8 + rloc) * V_ + kbase + uu * 8;

    f32x4 acc[2][2];
#pragma unroll
    for (int i = 0; i < 2; ++i)
#pragma unroll
        for (int j = 0; j < 2; ++j) acc[i][j] = (f32x4){0.f, 0.f, 0.f, 0.f};

    // prologue: B DMA for k0=0, A regs for k0=0
#pragma unroll
    for (int q = 0; q < 4; ++q)
        gload_lds16(bgbase + (size_t)q * 32 * V_, &Bs[(q * 32 + wv * 8) * BK]);
    float4 ap0 = *(const float4*)(aptr);
    float4 ap1 = *(const float4*)(aptr + 4);

    for (int k0 = 0; k0 < KHALF; k0 += BK) {
        bf16x8 av;
        av[0] = (bf16_t)ap0.x; av[1] = (bf16_t)ap0.y; av[2] = (bf16_t)ap0.z; av[3] = (bf16_t)ap0.w;
        av[4] = (bf16_t)ap1.x; av[5] = (bf16_t)ap1.y; av[6] = (bf16_t)ap1.z; av[7] = (bf16_t)ap1.w;
        *(bf16x8*)adst = av;
        __syncthreads();  // B DMA + A writes visible

        bf16x8 af[2][2], bfr[2][2];
#pragma unroll
        for (int i = 0; i < 2; ++i)
#pragma unroll
            for (int kf = 0; kf < 2; ++kf)
                af[i][kf] = *(bf16x8*)&As[(i * 16 + lm) * BK + (((kf * 4 + lq) ^ (lm & 7)) * 8)];
#pragma unroll
        for (int j = 0; j < 2; ++j)
#pragma unroll
            for (int kf = 0; kf < 2; ++kf)
                bfr[j][kf] = *(bf16x8*)&Bs[(n0w + j * 16 + lm) * BK + (((kf * 4 + lq) ^ (lm & 7)) * 8)];

        if (k0 + BK < KHALF) {  // A reg prefetch for next iter
            ap0 = *(const float4*)(aptr + k0 + BK);
            ap1 = *(const float4*)(aptr + k0 + BK + 4);
        }
#pragma unroll
        for (int i = 0; i < 2; ++i)
#pragma unroll
            for (int j = 0; j < 2; ++j) {
                acc[i][j] = __builtin_amdgcn_mfma_f32_16x16x32_bf16(af[i][0], bfr[j][0], acc[i][j], 0, 0, 0);
                acc[i][j] = __builtin_amdgcn_mfma_f32_16x16x32_bf16(af[i][1], bfr[j][1], acc[i][j], 0, 0, 0);
            }
        __syncthreads();  // done reading As/Bs
        if (k0 + BK < KHALF) {
#pragma unroll
            for (int q = 0; q < 4; ++q)
                gload_lds16(bgbase + (size_t)q * 32 * V_ + (k0 + BK), &Bs[(q * 32 + wv * 8) * BK]);
        }
    }
    // epilogue: raw partial store. C/D: n = lane&15 (+16j), m = lq*4 + reg (+16i)
#pragma unroll
    for (int j = 0; j < 2; ++j) {
        const int n = n0w + j * 16 + lm;
#pragma unroll
        for (int i = 0; i < 2; ++i)
#pragma unroll
            for (int r = 0; r < 4; ++r) {
                const int m = m0 + i * 16 + lq * 4 + r;
                LRh[(size_t)m * 128 + n] = acc[i][j][r];
            }
    }
}

// ---------------- kernel 3: fused bias/relu + d + Lbar + s ----------------
// row value: x[k] = relu(LRa[row][k] + LRb[row][k] + bias[k]),
// bias[k] = k<64 ? U1b[k] : U2b[k-64]. right = x[0..63], left = x[64..127].
__global__ __launch_bounds__(256) void kds(const float* __restrict__ LRa,
                                           const float* __restrict__ LRb,
                                           const float* __restrict__ U1b,
                                           const float* __restrict__ U2b,
                                           float* __restrict__ s) {
    __shared__ float dl[256];
    __shared__ float red[4][64];
    __shared__ float lbar[64];
    __shared__ float bias[128];
    const int b = blockIdx.x, t = threadIdx.x;
    if (t < 128) bias[t] = (t < 64) ? U1b[t] : U2b[t - 64];
    __syncthreads();
    const float* ra = LRa + (size_t)(b * N_ + t) * 128;
    const float* rb = LRb + (size_t)(b * N_ + t) * 128;
    // phase 0: d
    float dd = 0.f;
#pragma unroll
    for (int k = 0; k < 64; k += 4) {
        float4 xa = *(const float4*)(ra + k);
        float4 xb = *(const float4*)(rb + k);
        float4 ya = *(const float4*)(ra + 64 + k);
        float4 yb = *(const float4*)(rb + 64 + k);
        float r0 = fmaxf(xa.x + xb.x + bias[k + 0], 0.f);
        float r1 = fmaxf(xa.y + xb.y + bias[k + 1], 0.f);
        float r2 = fmaxf(xa.z + xb.z + bias[k + 2], 0.f);
        float r3 = fmaxf(xa.w + xb.w + bias[k + 3], 0.f);
        float l0 = fmaxf(ya.x + yb.x + bias[64 + k + 0], 0.f);
        float l1 = fmaxf(ya.y + yb.y + bias[64 + k + 1], 0.f);
        float l2 = fmaxf(ya.z + yb.z + bias[64 + k + 2], 0.f);
        float l3 = fmaxf(ya.w + yb.w + bias[64 + k + 3], 0.f);
        dd += r0 * l0 + r1 * l1 + r2 * l2 + r3 * l3;
    }
    const float dv = rsqrtf(dd + 1e-6f);
    dl[t] = dv;
    __syncthreads();
    // phase 1: lbar[k] = sum_n dl[n] * left[n][k]
    const int k = t & 63, g = t >> 6;
    const float bl = bias[64 + k];
    float acc = 0.f;
    for (int n = g; n < N_; n += 4) {
        size_t idx = (size_t)(b * N_ + n) * 128 + 64 + k;
        acc += dl[n] * fmaxf(LRa[idx] + LRb[idx] + bl, 0.f);
    }
    red[g][k] = acc;
    __syncthreads();
    if (t < 64) lbar[t] = red[0][t] + red[1][t] + red[2][t] + red[3][t];
    __syncthreads();
    // phase 2: s[t]
    float a2 = 0.f;
#pragma unroll 4
    for (int kk = 0; kk < 64; kk += 4) {
        float4 xa = *(const float4*)(ra + kk);
        float4 xb = *(const float4*)(rb + kk);
        a2 += lbar[kk + 0] * fmaxf(xa.x + xb.x + bias[kk + 0], 0.f)
            + lbar[kk + 1] * fmaxf(xa.y + xb.y + bias[kk + 1], 0.f)
            + lbar[kk + 2] * fmaxf(xa.z + xb.z + bias[kk + 2], 0.f)
            + lbar[kk + 3] * fmaxf(xa.w + xb.w + bias[kk + 3], 0.f);
    }
    s[b * N_ + t] = ((float)(N_ + 1) - dv * a2) * (1.0f / (float)N_);
}

// ---------------- kernel 4: featsT[v][b] += partial over m-chunk ----------
__global__ __launch_bounds__(256) void kfeats(const float* __restrict__ Vmat,
                                              const float* __restrict__ s,
                                              float* __restrict__ featsT) {
    const int b = blockIdx.x >> 3, vc = (blockIdx.x >> 2) & 1, mc = blockIdx.x & 3;
    __shared__ float sl[64];
    const int t = threadIdx.x;
    if (t < 64) sl[t] = s[b * N_ + mc * 64 + t];
    __syncthreads();
    const int v = vc * 1024 + t * 4;
    const float* base = Vmat + (size_t)b * N_ * V_ + (size_t)mc * 64 * V_ + v;
    float4 a = {0.f, 0.f, 0.f, 0.f};
    for (int m = 0; m < 64; m += 8) {
        float4 x[8];
#pragma unroll
        for (int u = 0; u < 8; ++u) x[u] = *(const float4*)(base + (size_t)(m + u) * V_);
#pragma unroll
        for (int u = 0; u < 8; ++u) {
            float sv = sl[m + u];
            a.x += sv * x[u].x; a.y += sv * x[u].y;
            a.z += sv * x[u].z; a.w += sv * x[u].w;
        }
    }
    atomicAdd(&featsT[(size_t)(v + 0) * 64 + b], a.x);
    atomicAdd(&featsT[(size_t)(v + 1) * 64 + b], a.y);
    atomicAdd(&featsT[(size_t)(v + 2) * 64 + b], a.z);
    atomicAdd(&featsT[(size_t)(v + 3) * 64 + b], a.w);
}

// ---------------- kernel 5: fused linear + BatchNorm ----------------------
// (b_lin dropped: constant per-column shift cancels in BatchNorm)
__global__ __launch_bounds__(256) void klinbn(const float* __restrict__ featsT,
                                              const float* __restrict__ Wl,
                                              const float* __restrict__ gamma,
                                              const float* __restrict__ beta,
                                              float* __restrict__ out) {
    __shared__ float red[4][4][64];
    const int e0 = blockIdx.x * 4;
    const int t = threadIdx.x, b = t & 63, g = t >> 6;
    const float* w0 = Wl + (size_t)(e0 + 0) * V_ + g * 512;
    const float* w1 = Wl + (size_t)(e0 + 1) * V_ + g * 512;
    const float* w2 = Wl + (size_t)(e0 + 2) * V_ + g * 512;
    const float* w3 = Wl + (size_t)(e0 + 3) * V_ + g * 512;
    const float* f = featsT + (size_t)g * 512 * 64 + b;
    float a0 = 0.f, a1 = 0.f, a2 = 0.f, a3 = 0.f;
#pragma unroll 4
    for (int k = 0; k < 512; ++k) {
        float fv = f[(size_t)k * 64];
        a0 += fv * w0[k]; a1 += fv * w1[k]; a2 += fv * w2[k]; a3 += fv * w3[k];
    }
    red[g][0][b] = a0; red[g][1][b] = a1; red[g][2][b] = a2; red[g][3][b] = a3;
    __syncthreads();
    const int e = t >> 6;  // wave e owns e-row e0+e across lanes b
    float v = red[0][e][b] + red[1][e][b] + red[2][e][b] + red[3][e][b];
    float sum = v;
#pragma unroll
    for (int o = 1; o < 64; o <<= 1) sum += __shfl_xor(sum, o, 64);
    float mu = sum * (1.f / 64.f);
    float dvv = v - mu;
    float q = dvv * dvv;
#pragma unroll
    for (int o = 1; o < 64; o <<= 1) q += __shfl_xor(q, o, 64);
    float inv = rsqrtf(q * (1.f / 64.f) + 1e-5f);
    float res = gamma[e0 + e] * dvv * inv + beta[e0 + e];
    __syncthreads();
    red[0][e][b] = res;
    __syncthreads();
    const int b2 = t >> 2, j = t & 3;
    out[(size_t)b2 * E_ + e0 + j] = red[0][j][b2];
}

extern "C" void kernel_launch(void* const* d_in, const int* in_sizes, int n_in,
                              void* d_out, int out_size, void* d_ws, size_t ws_size,
                              hipStream_t stream) {
    const float* Vmat = (const float*)d_in[0];
    const float* U1v  = (const float*)d_in[1];
    const float* U1g  = (const float*)d_in[2];
    const float* U1b  = (const float*)d_in[3];
    const float* U2v  = (const float*)d_in[4];
    const float* U2g  = (const float*)d_in[5];
    const float* U2b  = (const float*)d_in[6];
    const float* Wl   = (const float*)d_in[7];
    // d_in[8] = b_lin: unused (cancels in BatchNorm)
    const float* gam  = (const float*)d_in[9];
    const float* bet  = (const float*)d_in[10];

    float*  ws     = (float*)d_ws;
    float*  s      = ws + OFF_S;
    float*  LRa    = ws + OFF_LR;
    float*  LRb    = ws + OFF_LR + LRHALF;
    float*  featsT = ws + OFF_FT;
    bf16_t* Wb     = (bf16_t*)(ws + OFF_WB);

    kprep  <<<128, 256, 0, stream>>>(U1v, U1g, U2v, U2g, Wb, featsT);
    gemm_lr<<<dim3(MROWS / 32, 2), 256, 0, stream>>>(Vmat, Wb, LRa);
    kds    <<<B_, 256, 0, stream>>>(LRa, LRb, U1b, U2b, s);
    kfeats <<<B_ * 8, 256, 0, stream>>>(Vmat, s, featsT);
    klinbn <<<E_ / 4, 256, 0, stream>>>(featsT, Wl, gam, bet, (float*)d_out);
}